// Round 1
// baseline (182.866 us; speedup 1.0000x reference)
//
#include <hip/hip_runtime.h>
#include <hip/hip_bf16.h>

// B=32 L=1024 D=128 H=128 W=9 F=137. Output f32 (32,1024,128).
// ws layout: W12Bt bf16[256][128] @0 (64KB); CwBt bf16[128][1152] @65536 (288KB);
//            wt f32[32768][9] @360448 (1.18MB); FG f32[32768][256] @1540096 (33.5MB)

typedef __attribute__((ext_vector_type(8))) short bf16x8;
typedef __attribute__((ext_vector_type(4))) float f32x4;

#define LL 1024
#define DD 128
#define HH 128

__device__ __forceinline__ unsigned short f2bf(float f) {
  unsigned int u = __float_as_uint(f);
  u = u + 0x7FFFu + ((u >> 16) & 1u);   // RNE
  return (unsigned short)(u >> 16);
}

// ---------- prep: build bf16 K-contiguous weight copies ----------
__global__ __launch_bounds__(256) void prep_kernel(
    const float* __restrict__ w1, const float* __restrict__ w2,
    const float* __restrict__ cnn,
    unsigned short* __restrict__ W12Bt, unsigned short* __restrict__ CwBt) {
  int gid = blockIdx.x * 256 + threadIdx.x;
  if (blockIdx.x < 128) {            // 32768 elements: W12Bt[n][d]
    int n = gid >> 7, d = gid & 127;
    float v = (n < 128) ? w1[d * 128 + n] : w2[d * 128 + (n - 128)];
    W12Bt[n * 128 + d] = f2bf(v);
  } else {                           // 147456 elements: CwBt[h][w*128+d]
    int idx = gid - 32768;
    int h = idx / 1152;
    int c = idx - h * 1152;
    int w = c >> 7, d = c & 127;
    CwBt[h * 1152 + c] = f2bf(cnn[(w * 137 + d) * 128 + h]);
  }
}

// ---------- GEMM1: FG[row][0:128]=emb@w1d, [128:256]=emb@w2d ----------
__global__ __launch_bounds__(256) void gemm_fg_kernel(
    const float* __restrict__ emb, const unsigned short* __restrict__ W12Bt,
    float* __restrict__ FG) {
  __shared__ uint4 As[2048];   // [128 rows][16 granules] swizzled, bf16 K-contig
  __shared__ uint4 Bs[2048];
  int tid = threadIdx.x;
  int row0 = blockIdx.x * 128;
  int ny = blockIdx.y;               // 0: f-half, 1: g-half
  int tr = tid >> 4, g = tid & 15;
  #pragma unroll
  for (int p = 0; p < 8; ++p) {
    int r = p * 16 + tr;
    const float4* src = (const float4*)(emb + (size_t)(row0 + r) * DD + g * 8);
    float4 x0 = src[0], x1 = src[1];
    uint4 v;
    v.x = f2bf(x0.x) | ((unsigned)f2bf(x0.y) << 16);
    v.y = f2bf(x0.z) | ((unsigned)f2bf(x0.w) << 16);
    v.z = f2bf(x1.x) | ((unsigned)f2bf(x1.y) << 16);
    v.w = f2bf(x1.z) | ((unsigned)f2bf(x1.w) << 16);
    As[r * 16 + (g ^ (r & 7))] = v;
    Bs[r * 16 + (g ^ (r & 7))] =
        *(const uint4*)(W12Bt + (size_t)(ny * 128 + r) * 128 + g * 8);
  }
  __syncthreads();
  int lane = tid & 63, wid = tid >> 6;
  int wr = wid >> 1, wc = wid & 1;
  int rbase = wr * 64 + (lane & 15);
  int cbase = wc * 64 + (lane & 15);
  int kg = lane >> 4;
  f32x4 acc[4][4];
  const f32x4 z = {0.f, 0.f, 0.f, 0.f};
  #pragma unroll
  for (int m = 0; m < 4; ++m)
    #pragma unroll
    for (int n = 0; n < 4; ++n) acc[m][n] = z;
  const bf16x8* Asb = (const bf16x8*)As;
  const bf16x8* Bsb = (const bf16x8*)Bs;
  #pragma unroll
  for (int kk = 0; kk < 4; ++kk) {
    int gk = kk * 4 + kg;
    bf16x8 aF[4], bF[4];
    #pragma unroll
    for (int m = 0; m < 4; ++m) {
      int ar = rbase + m * 16;
      aF[m] = Asb[ar * 16 + (gk ^ (ar & 7))];
      int bc = cbase + m * 16;
      bF[m] = Bsb[bc * 16 + (gk ^ (bc & 7))];
    }
    #pragma unroll
    for (int m = 0; m < 4; ++m)
      #pragma unroll
      for (int n = 0; n < 4; ++n)
        acc[m][n] = __builtin_amdgcn_mfma_f32_16x16x32_bf16(aF[m], bF[n], acc[m][n], 0, 0, 0);
  }
  int hq = lane >> 4;
  #pragma unroll
  for (int m = 0; m < 4; ++m)
    #pragma unroll
    for (int n = 0; n < 4; ++n) {
      int h = wc * 64 + n * 16 + (lane & 15);
      #pragma unroll
      for (int j = 0; j < 4; ++j) {
        int row = row0 + wr * 64 + m * 16 + hq * 4 + j;
        FG[(size_t)row * 256 + ny * 128 + h] = acc[m][n][j];
      }
    }
}

// ---------- weights: tanh-score + softmax over 9 positions ----------
__global__ __launch_bounds__(256) void weights_kernel(
    const float* __restrict__ FG,
    const float* __restrict__ w1, const float* __restrict__ w1b,
    const float* __restrict__ w2, const float* __restrict__ w2b,
    const float* __restrict__ vw, float* __restrict__ wt) {
  int tid = threadIdx.x;
  int row = blockIdx.x * 4 + (tid >> 6);   // one wave per row
  int lane = tid & 63;
  int b = row >> 10, l = row & 1023;
  size_t fo = (size_t)row * 256;
  float e0 = FG[fo + lane]      + w1[132 * 128 + lane]      + w1b[lane];
  float e1 = FG[fo + 64 + lane] + w1[132 * 128 + 64 + lane] + w1b[64 + lane];
  float vw0 = vw[lane], vw1 = vw[64 + lane];
  float s[9];
  #pragma unroll
  for (int w = 0; w < 9; ++w) {
    int t = l + w - 4;
    float g0 = 0.f, g1 = 0.f;
    if (t >= 0 && t < LL) {
      size_t go = (size_t)(b * LL + t) * 256;
      g0 = FG[go + 128 + lane];
      g1 = FG[go + 192 + lane];
    }
    float p0 = w2[(128 + w) * 128 + lane]      + w2b[lane];
    float p1 = w2[(128 + w) * 128 + 64 + lane] + w2b[64 + lane];
    float v = tanhf(e0 + g0 + p0) * vw0 + tanhf(e1 + g1 + p1) * vw1;
    #pragma unroll
    for (int off = 32; off > 0; off >>= 1) v += __shfl_xor(v, off, 64);
    s[w] = v;   // all lanes hold full sum (v_b omitted: softmax-invariant)
  }
  float mx = s[0];
  #pragma unroll
  for (int w = 1; w < 9; ++w) mx = fmaxf(mx, s[w]);
  float sum = 0.f;
  #pragma unroll
  for (int w = 0; w < 9; ++w) { s[w] = __expf(s[w] - mx); sum += s[w]; }
  float inv = 1.f / sum;
  if (lane == 0) {
    #pragma unroll
    for (int w = 0; w < 9; ++w) wt[(size_t)row * 9 + w] = s[w] * inv;
  }
}

// ---------- GEMM2 (fused): out = X@CwB + pos/bias, X built on the fly ----------
__global__ __launch_bounds__(256) void gemm_out_kernel(
    const float* __restrict__ emb, const unsigned short* __restrict__ CwBt,
    const float* __restrict__ wt, const float* __restrict__ cnn,
    const float* __restrict__ cnnb, float* __restrict__ out) {
  __shared__ uint4 As[2048];
  __shared__ uint4 Bs[2048];
  int tid = threadIdx.x;
  int row0 = blockIdx.x * 128;     // 128-row tiles never cross batch (1024 | 128)
  int bb = row0 >> 10;
  int l0 = row0 & 1023;
  int tr = tid >> 4, g = tid & 15;
  int lane = tid & 63, wid = tid >> 6;
  int wr = wid >> 1, wc = wid & 1;
  int rbase = wr * 64 + (lane & 15);
  int cbase = wc * 64 + (lane & 15);
  int kg = lane >> 4;
  f32x4 acc[4][4];
  const f32x4 z = {0.f, 0.f, 0.f, 0.f};
  #pragma unroll
  for (int m = 0; m < 4; ++m)
    #pragma unroll
    for (int n = 0; n < 4; ++n) acc[m][n] = z;
  const bf16x8* Asb = (const bf16x8*)As;
  const bf16x8* Bsb = (const bf16x8*)Bs;
  for (int w = 0; w < 9; ++w) {
    __syncthreads();
    #pragma unroll
    for (int p = 0; p < 8; ++p) {
      int r = p * 16 + tr;
      int t = l0 + r + w - 4;
      uint4 v = {0u, 0u, 0u, 0u};
      if (t >= 0 && t < LL) {
        float sc = wt[(size_t)(row0 + r) * 9 + w];
        const float4* src = (const float4*)(emb + (size_t)(bb * LL + t) * DD + g * 8);
        float4 x0 = src[0], x1 = src[1];
        v.x = f2bf(x0.x * sc) | ((unsigned)f2bf(x0.y * sc) << 16);
        v.y = f2bf(x0.z * sc) | ((unsigned)f2bf(x0.w * sc) << 16);
        v.z = f2bf(x1.x * sc) | ((unsigned)f2bf(x1.y * sc) << 16);
        v.w = f2bf(x1.z * sc) | ((unsigned)f2bf(x1.w * sc) << 16);
      }
      As[r * 16 + (g ^ (r & 7))] = v;
      Bs[r * 16 + (g ^ (r & 7))] =
          *(const uint4*)(CwBt + (size_t)r * 1152 + w * 128 + g * 8);
    }
    __syncthreads();
    #pragma unroll
    for (int kk = 0; kk < 4; ++kk) {
      int gk = kk * 4 + kg;
      bf16x8 aF[4], bF[4];
      #pragma unroll
      for (int m = 0; m < 4; ++m) {
        int ar = rbase + m * 16;
        aF[m] = Asb[ar * 16 + (gk ^ (ar & 7))];
        int bc = cbase + m * 16;
        bF[m] = Bsb[bc * 16 + (gk ^ (bc & 7))];
      }
      #pragma unroll
      for (int m = 0; m < 4; ++m)
        #pragma unroll
        for (int n = 0; n < 4; ++n)
          acc[m][n] = __builtin_amdgcn_mfma_f32_16x16x32_bf16(aF[m], bF[n], acc[m][n], 0, 0, 0);
    }
  }
  int hq = lane >> 4;
  #pragma unroll
  for (int n = 0; n < 4; ++n) {
    int h = wc * 64 + n * 16 + (lane & 15);
    float cp[9];
    #pragma unroll
    for (int w = 0; w < 9; ++w) cp[w] = cnn[(size_t)(w * 138 + 128) * 128 + h];
    float cb = cnnb[h];
    #pragma unroll
    for (int m = 0; m < 4; ++m) {
      int rb2 = row0 + wr * 64 + m * 16 + hq * 4;
      #pragma unroll
      for (int j = 0; j < 4; ++j) {
        int row = rb2 + j;
        float s2 = acc[m][n][j] + cb;
        const float* wrow = wt + (size_t)row * 9;
        #pragma unroll
        for (int w = 0; w < 9; ++w) s2 += wrow[w] * cp[w];
        out[(size_t)row * HH + h] = s2;
      }
    }
  }
}

extern "C" void kernel_launch(void* const* d_in, const int* in_sizes, int n_in,
                              void* d_out, int out_size, void* d_ws, size_t ws_size,
                              hipStream_t stream) {
  const float* emb  = (const float*)d_in[0];
  // d_in[1] masks: unused by reference
  const float* w1   = (const float*)d_in[2];
  const float* w1b  = (const float*)d_in[3];
  const float* w2   = (const float*)d_in[4];
  const float* w2b  = (const float*)d_in[5];
  const float* vw   = (const float*)d_in[6];
  // d_in[7] v_b: softmax-invariant, unused
  const float* cnn  = (const float*)d_in[8];
  const float* cnnb = (const float*)d_in[9];
  float* out = (float*)d_out;

  char* ws = (char*)d_ws;
  unsigned short* W12Bt = (unsigned short*)(ws);
  unsigned short* CwBt  = (unsigned short*)(ws + 65536);
  float* wtbuf          = (float*)(ws + 360448);
  float* FG             = (float*)(ws + 1540096);

  prep_kernel<<<704, 256, 0, stream>>>(w1, w2, cnn, W12Bt, CwBt);
  gemm_fg_kernel<<<dim3(256, 2), 256, 0, stream>>>(emb, W12Bt, FG);
  weights_kernel<<<8192, 256, 0, stream>>>(FG, w1, w1b, w2, w2b, vw, wtbuf);
  gemm_out_kernel<<<256, 256, 0, stream>>>(emb, CwBt, wtbuf, cnn, cnnb, out);
}

// Round 2
// 137.411 us; speedup vs baseline: 1.3308x; 1.3308x over previous
//
#include <hip/hip_runtime.h>
#include <hip/hip_bf16.h>

// B=32 L=1024 D=128 H=128 W=9 F=137. Output f32 (32,1024,128).
// ws: W12Bt bf16[256][128] @0 (64KB); CwBt bf16[128][1152] @65536 (288KB).
// mega kernel LDS pool (dynamic, 115200B):
//   E    @0      uint4[144*16]  : emb rows l0-4..l0+139 as bf16, XOR-swizzled granules
//   wtT  @36864  f32[9][128]    : softmax weights, transposed
//   HB   @41472  union: W12lds bf16[256][16gran] (64KB) / H bf16[2][144][128] (72KB)
//                     / Bs bf16[128][16gran] (32KB)

typedef __attribute__((ext_vector_type(8))) short bf16x8;
typedef __attribute__((ext_vector_type(4))) float f32x4;

#define LL 1024

__device__ __forceinline__ unsigned short f2bf(float f) {
  unsigned int u = __float_as_uint(f);
  u = u + 0x7FFFu + ((u >> 16) & 1u);   // RNE
  return (unsigned short)(u >> 16);
}
__device__ __forceinline__ float bf2f(unsigned short us) {
  return __uint_as_float(((unsigned int)us) << 16);
}
__device__ __forceinline__ float fast_tanh(float x) {
  float e = __expf(2.f * x);                       // inf-safe: e=inf -> 1, e=0 -> -1
  return 1.f - 2.f * __builtin_amdgcn_rcpf(e + 1.f);
}

// ---------- prep: bf16 K-contiguous weight copies (unchanged, proven) ----------
__global__ __launch_bounds__(256) void prep_kernel(
    const float* __restrict__ w1, const float* __restrict__ w2,
    const float* __restrict__ cnn,
    unsigned short* __restrict__ W12Bt, unsigned short* __restrict__ CwBt) {
  int gid = blockIdx.x * 256 + threadIdx.x;
  if (blockIdx.x < 128) {            // 32768: W12Bt[n][d]  (n<128: w1 col, else w2 col)
    int n = gid >> 7, d = gid & 127;
    float v = (n < 128) ? w1[d * 128 + n] : w2[d * 128 + (n - 128)];
    W12Bt[n * 128 + d] = f2bf(v);
  } else {                           // 147456: CwBt[h][w*128+d]
    int idx = gid - 32768;
    int h = idx / 1152;
    int c = idx - h * 1152;
    int w = c >> 7, d = c & 127;
    CwBt[h * 1152 + c] = f2bf(cnn[(w * 137 + d) * 128 + h]);
  }
}

// ---------- mega: E-stage -> H=E@W12 -> weights -> fused out-GEMM ----------
__global__ __launch_bounds__(512, 2) void mega_kernel(
    const float* __restrict__ emb,
    const unsigned short* __restrict__ W12Bt,
    const unsigned short* __restrict__ CwBt,
    const float* __restrict__ w1, const float* __restrict__ w1b,
    const float* __restrict__ w2, const float* __restrict__ w2b,
    const float* __restrict__ vw,
    const float* __restrict__ cnn, const float* __restrict__ cnnb,
    float* __restrict__ out) {
  extern __shared__ __align__(16) unsigned char smem[];
  uint4* E   = (uint4*)smem;                               // 36864 B
  float* wtT = (float*)(smem + 36864);                     // 4608 B
  uint4* HB  = (uint4*)(smem + 41472);                     // 73728 B union region
  unsigned short* H = (unsigned short*)(smem + 41472);

  int tid = threadIdx.x;
  int bid = blockIdx.x;
  int b = bid >> 3, l0 = (bid & 7) << 7;
  int lane = tid & 63, wid = tid >> 6;
  int l15 = lane & 15, l4 = lane >> 4;

  // ---- phase 0: stage E (144 rows, emb rows l0-4..l0+139, OOB=0) + W12lds ----
  #pragma unroll
  for (int s = 0; s < 5; ++s) {
    int i = tid + s * 512;
    if (i < 2304) {
      int er = i >> 4, g = i & 15;
      int t = l0 + er - 4;
      uint4 v = {0u, 0u, 0u, 0u};
      if (t >= 0 && t < LL) {
        const float4* src = (const float4*)(emb + ((size_t)(b * LL + t) << 7) + g * 8);
        float4 x0 = src[0], x1 = src[1];
        v.x = f2bf(x0.x) | ((unsigned)f2bf(x0.y) << 16);
        v.y = f2bf(x0.z) | ((unsigned)f2bf(x0.w) << 16);
        v.z = f2bf(x1.x) | ((unsigned)f2bf(x1.y) << 16);
        v.w = f2bf(x1.z) | ((unsigned)f2bf(x1.w) << 16);
      }
      E[er * 16 + (g ^ (er & 7))] = v;
    }
  }
  #pragma unroll
  for (int s = 0; s < 8; ++s) {
    int i = tid + s * 512;           // 4096 granules = 64KB
    int n = i >> 4, g = i & 15;
    HB[n * 16 + (g ^ (n & 7))] = *(const uint4*)(W12Bt + n * 128 + g * 8);
  }
  __syncthreads();

  // ---- phase 2: H[0]=E@w1d (rows 0..143), H[1]=E@w2d ----
  const bf16x8* Eb = (const bf16x8*)E;
  const bf16x8* Wb = (const bf16x8*)HB;
  f32x4 acc[3][8];
  #pragma unroll
  for (int it = 0; it < 3; ++it) {
    int rt = wid + it * 8;           // 18 row-tiles: 0..8 -> H1, 9..17 -> H2
    if (rt < 18) {
      int part = rt >= 9;
      int er0 = (part ? rt - 9 : rt) * 16;
      int nbase = part << 7;
      #pragma unroll
      for (int nn = 0; nn < 8; ++nn) acc[it][nn] = (f32x4){0.f, 0.f, 0.f, 0.f};
      #pragma unroll
      for (int kk = 0; kk < 4; ++kk) {
        int er = er0 + l15;
        bf16x8 aF = Eb[er * 16 + ((kk * 4 + l4) ^ (er & 7))];
        #pragma unroll
        for (int nn = 0; nn < 8; ++nn) {
          int n = nbase + nn * 16 + l15;
          bf16x8 bF = Wb[n * 16 + ((kk * 4 + l4) ^ (n & 7))];
          acc[it][nn] = __builtin_amdgcn_mfma_f32_16x16x32_bf16(aF, bF, acc[it][nn], 0, 0, 0);
        }
      }
    }
  }
  __syncthreads();   // all MFMA reads of W12lds done -> safe to overwrite with H
  #pragma unroll
  for (int it = 0; it < 3; ++it) {
    int rt = wid + it * 8;
    if (rt < 18) {
      int part = rt >= 9;
      int er0 = (part ? rt - 9 : rt) * 16;
      #pragma unroll
      for (int nn = 0; nn < 8; ++nn)
        #pragma unroll
        for (int j = 0; j < 4; ++j)
          H[part * 18432 + (er0 + l4 * 4 + j) * 128 + nn * 16 + l15] = f2bf(acc[it][nn][j]);
    }
  }
  __syncthreads();

  // ---- phase 3: weights (wave-uniform row; all lanes redundant softmax) ----
  {
    float c1_0 = w1[132 * 128 + lane] + w1b[lane];
    float c1_1 = w1[132 * 128 + 64 + lane] + w1b[64 + lane];
    float vw0 = vw[lane], vw1 = vw[64 + lane];
    float pw0[9], pw1[9];
    #pragma unroll
    for (int w = 0; w < 9; ++w) {
      pw0[w] = w2[(128 + w) * 128 + lane] + w2b[lane];
      pw1[w] = w2[(128 + w) * 128 + 64 + lane] + w2b[64 + lane];
    }
    const unsigned short* H1 = H;
    const unsigned short* H2 = H + 18432;
    for (int rr = 0; rr < 16; ++rr) {
      int r = wid * 16 + rr;
      float f0 = bf2f(H1[(r + 4) * 128 + lane]) + c1_0;
      float f1 = bf2f(H1[(r + 4) * 128 + 64 + lane]) + c1_1;
      float s[9];
      #pragma unroll
      for (int w = 0; w < 9; ++w) {
        float g0 = bf2f(H2[(r + w) * 128 + lane]);
        float g1 = bf2f(H2[(r + w) * 128 + 64 + lane]);
        float v = fast_tanh(f0 + g0 + pw0[w]) * vw0 + fast_tanh(f1 + g1 + pw1[w]) * vw1;
        #pragma unroll
        for (int off = 32; off; off >>= 1) v += __shfl_xor(v, off, 64);
        s[w] = v;
      }
      float mx = s[0];
      #pragma unroll
      for (int w = 1; w < 9; ++w) mx = fmaxf(mx, s[w]);
      float sum = 0.f;
      #pragma unroll
      for (int w = 0; w < 9; ++w) { s[w] = __expf(s[w] - mx); sum += s[w]; }
      float inv = __builtin_amdgcn_rcpf(sum);
      float wv = s[0];
      #pragma unroll
      for (int w = 1; w < 9; ++w) wv = (lane == w) ? s[w] : wv;
      if (lane < 9) wtT[lane * 128 + r] = wv * inv;
    }
  }

  // ---- phase 4: out-GEMM, unscaled A from E, wt applied in register epilogue ----
  int wr = wid >> 2, wc = wid & 3;   // wave tile: 64 rows x 32 h
  int h0 = wc * 32 + l15;
  float cb0 = cnnb[h0], cb1 = cnnb[h0 + 16];
  f32x4 fin[4][2];
  #pragma unroll
  for (int m = 0; m < 4; ++m)
    #pragma unroll
    for (int n = 0; n < 2; ++n) fin[m][n] = (f32x4){0.f, 0.f, 0.f, 0.f};
  const bf16x8* Bb = (const bf16x8*)HB;

  for (int w = 0; w < 9; ++w) {
    __syncthreads();                 // prev readers of Bs/H done
    #pragma unroll
    for (int s = 0; s < 4; ++s) {    // stage Bs: 2048 granules
      int i = tid + s * 512;
      int hh = i >> 4, g = i & 15;
      HB[hh * 16 + (g ^ (hh & 7))] = *(const uint4*)(CwBt + hh * 1152 + w * 128 + g * 8);
    }
    float cp0 = cnn[(w * 138 + 128) * 128 + h0];        // pos-onehot column term
    float cp1 = cnn[(w * 138 + 128) * 128 + h0 + 16];
    __syncthreads();
    f32x4 tmp[4][2];
    #pragma unroll
    for (int m = 0; m < 4; ++m)
      #pragma unroll
      for (int n = 0; n < 2; ++n) tmp[m][n] = (f32x4){0.f, 0.f, 0.f, 0.f};
    #pragma unroll
    for (int kk = 0; kk < 4; ++kk) {
      bf16x8 aF[4];
      #pragma unroll
      for (int m = 0; m < 4; ++m) {
        int er = wr * 64 + m * 16 + l15 + w;
        aF[m] = Eb[er * 16 + ((kk * 4 + l4) ^ (er & 7))];
      }
      #pragma unroll
      for (int n = 0; n < 2; ++n) {
        int hh = wc * 32 + n * 16 + l15;
        bf16x8 bF = Bb[hh * 16 + ((kk * 4 + l4) ^ (hh & 7))];
        #pragma unroll
        for (int m = 0; m < 4; ++m)
          tmp[m][n] = __builtin_amdgcn_mfma_f32_16x16x32_bf16(aF[m], bF, tmp[m][n], 0, 0, 0);
      }
    }
    #pragma unroll
    for (int m = 0; m < 4; ++m) {
      f32x4 wt4 = *(const f32x4*)(wtT + w * 128 + wr * 64 + m * 16 + l4 * 4);
      #pragma unroll
      for (int j = 0; j < 4; ++j) {
        fin[m][0][j] += wt4[j] * (tmp[m][0][j] + cp0);
        fin[m][1][j] += wt4[j] * (tmp[m][1][j] + cp1);
      }
    }
  }
  // epilogue
  #pragma unroll
  for (int m = 0; m < 4; ++m)
    #pragma unroll
    for (int j = 0; j < 4; ++j) {
      int r = wr * 64 + m * 16 + l4 * 4 + j;
      size_t o = ((size_t)(b * LL + l0 + r) << 7) + h0;
      out[o]      = fin[m][0][j] + cb0;
      out[o + 16] = fin[m][1][j] + cb1;
    }
}

extern "C" void kernel_launch(void* const* d_in, const int* in_sizes, int n_in,
                              void* d_out, int out_size, void* d_ws, size_t ws_size,
                              hipStream_t stream) {
  const float* emb  = (const float*)d_in[0];
  // d_in[1] masks: unused by reference
  const float* w1   = (const float*)d_in[2];
  const float* w1b  = (const float*)d_in[3];
  const float* w2   = (const float*)d_in[4];
  const float* w2b  = (const float*)d_in[5];
  const float* vw   = (const float*)d_in[6];
  // d_in[7] v_b: softmax-invariant, unused
  const float* cnn  = (const float*)d_in[8];
  const float* cnnb = (const float*)d_in[9];
  float* out = (float*)d_out;

  char* ws = (char*)d_ws;
  unsigned short* W12Bt = (unsigned short*)(ws);
  unsigned short* CwBt  = (unsigned short*)(ws + 65536);

  prep_kernel<<<704, 256, 0, stream>>>(w1, w2, cnn, W12Bt, CwBt);
  mega_kernel<<<256, 512, 115200, stream>>>(emb, W12Bt, CwBt, w1, w1b, w2, w2b,
                                            vw, cnn, cnnb, out);
}